// Round 1
// 568.921 us; speedup vs baseline: 1.0073x; 1.0073x over previous
//
#include <hip/hip_runtime.h>
#include <math.h>

#define NT 1024
#define NQ 128
#define FDIM 576
#define NGROUP 192
#define F4 (FDIM / 4)          // 144 float4 per (t,q) row
#define NTHREADS 512           // 8 waves/block; 4 blocks/CU => 32 waves/CU resident
#define NWAVES (NTHREADS / 64)

__global__ __launch_bounds__(NTHREADS, 8) void energy_kernel(
    const float* __restrict__ T,        // [NT, 7]
    const float* __restrict__ desc,     // [NT, NQ, FDIM]
    const float* __restrict__ qfeat,    // [NT, NQ, FDIM]
    const float* __restrict__ att,      // [NQ]
    const float* __restrict__ logit,    // [NGROUP]
    const float* __restrict__ ranges,   // [3,2] = {min0,max0,min1,max1,min2,max2}
    float* __restrict__ out)            // [NT]
{
    __shared__ float s_w[FDIM];
    __shared__ float s_att[NQ];
    __shared__ float s_red[NWAVES];

    const int tid = threadIdx.x;
    const int t = blockIdx.x;
    const float LN2 = 0.6931471805599453f;

    // Per-element weight table: w[e] = 2*softplus(logit[group(e)]) / (LN2*NGROUP)
    for (int e = tid; e < FDIM; e += NTHREADS) {
        int g;
        if (e < 64)       g = e;                    // l=0, d=1
        else if (e < 256) g = 64 + (e - 64) / 3;    // l=1, d=3
        else              g = 128 + (e - 256) / 5;  // l=2, d=5
        float x = logit[g];
        float sp = (x > 20.0f) ? x : log1pf(expf(x));   // softplus, overflow-safe
        s_w[e] = 2.0f * sp / (LN2 * (float)NGROUP);
    }
    if (tid < NQ) s_att[tid] = att[tid];
    __syncthreads();

    const float4* __restrict__ d4 = (const float4*)(desc  + (size_t)t * NQ * FDIM);
    const float4* __restrict__ q4 = (const float4*)(qfeat + (size_t)t * NQ * FDIM);

    float acc = 0.0f;
    // NQ*F4 = 18432 total float4 pairs; 36 iterations per thread, coalesced.
    #pragma unroll 4
    for (int idx = tid; idx < NQ * F4; idx += NTHREADS) {
        const int q  = idx / F4;
        const int e4 = idx - q * F4;
        float4 a = d4[idx];
        float4 b = q4[idx];
        const float w0 = s_w[e4 * 4 + 0];
        const float w1 = s_w[e4 * 4 + 1];
        const float w2 = s_w[e4 * 4 + 2];
        const float w3 = s_w[e4 * 4 + 3];
        const float dx = a.x - b.x;
        const float dy = a.y - b.y;
        const float dz = a.z - b.z;
        const float dw = a.w - b.w;
        acc += s_att[q] * (w0 * dx * dx + w1 * dy * dy + w2 * dz * dz + w3 * dw * dw);
    }

    // Wave (64-lane) shuffle reduction
    #pragma unroll
    for (int off = 32; off > 0; off >>= 1)
        acc += __shfl_down(acc, off, 64);

    const int wave = tid >> 6;
    if ((tid & 63) == 0) s_red[wave] = acc;
    __syncthreads();

    if (tid == 0) {
        float total = 0.0f;
        #pragma unroll
        for (int w = 0; w < NWAVES; ++w) total += s_red[w];

        // Range sentinel: energy := 1e5 if any of T[t,4:7] outside ranges.
        // !(max>=x && x>=min) is true for NaN, matching jnp any(~in_range).
        const float x0 = T[t * 7 + 4];
        const float x1 = T[t * 7 + 5];
        const float x2 = T[t * 7 + 6];
        bool bad = !(ranges[1] >= x0 && x0 >= ranges[0]) ||
                   !(ranges[3] >= x1 && x1 >= ranges[2]) ||
                   !(ranges[5] >= x2 && x2 >= ranges[4]);
        out[t] = bad ? 100000.0f : total;
    }
}

extern "C" void kernel_launch(void* const* d_in, const int* in_sizes, int n_in,
                              void* d_out, int out_size, void* d_ws, size_t ws_size,
                              hipStream_t stream) {
    const float* T      = (const float*)d_in[0];
    const float* desc   = (const float*)d_in[1];
    const float* qfeat  = (const float*)d_in[2];
    const float* att    = (const float*)d_in[3];
    const float* logit  = (const float*)d_in[4];
    const float* ranges = (const float*)d_in[5];
    float* out = (float*)d_out;

    energy_kernel<<<NT, NTHREADS, 0, stream>>>(T, desc, qfeat, att, logit, ranges, out);
}